// Round 2
// baseline (732.456 us; speedup 1.0000x reference)
//
#include <hip/hip_runtime.h>
#include <hip/hip_cooperative_groups.h>

namespace cg = cooperative_groups;

// Problem constants (all inputs/outputs fp32, proven earlier)
#define NN    8192   // nodes
#define FIN   256    // input features
#define UNITS 64
#define HEADS 4
#define CTOT  256    // HEADS*UNITS
#define CAP   256    // max edges/row (deg ~ Bin(8192,.004)+self: mean 34, sd 5.7)

// Fused cooperative kernel geometry: 1024 blocks = 4 blocks/CU x 256 CUs.
// Residency proof: LDS ~27 KB/block (<40 KB = 160/4), __launch_bounds__(256,4)
// caps VGPR at 128 (4 waves/SIMD), waves 16/CU <= 32.  => 4 blocks/CU resident.
#define GRID  1024
#define GBLK  512    // GEMM tile blocks (128 row-tiles x 4 heads)
#define RA1   6      // phase-A scan rows per GEMM block   (512*6  = 3072)
#define RA2   10     // phase-A scan rows per scan-only blk (512*10 = 5120)
#define RB    8      // phase-B GAT rows per block          (1024*8 = 8192)

__global__ __launch_bounds__(256, 4) void k_fused(
    const float* __restrict__ X,    const float* __restrict__ W,
    const float* __restrict__ atts, const float* __restrict__ attn,
    const float* __restrict__ A,
    float* __restrict__ feats, float* __restrict__ s_self, float* __restrict__ s_neigh,
    int*   __restrict__ ej_g,  int*   __restrict__ cnt_g,
    float* __restrict__ out)
{
    __shared__ float Xt[32 * 68];        // GEMM staging [k][row], stride 68
    __shared__ float Wl[32 * 68];        // GEMM staging [k][u]
    __shared__ float reds[64], redn[64];
    __shared__ int   ej[CAP];
    __shared__ int   cnt;
    __shared__ float sc[HEADS][CAP];
    __shared__ float part[HEADS][CTOT];
    __shared__ float rls[HEADS];

    const int tid = threadIdx.x;
    const int bid = blockIdx.x;

    // ================= Phase A1: projection GEMM (blocks < GBLK) =================
    // VALU-bound; overlaps with the HBM-bound A-scan running on the other blocks.
    if (bid < GBLK) {
        const int rt = bid & 127;        // row tile
        const int h  = bid >> 7;         // head
        const int r0 = rt * 64;

        const int r  = (tid & 15) * 4;   // micro-tile row base
        const int cl = (tid >> 4) * 4;   // micro-tile col base
        const int srow = tid >> 2;       // 0..63
        const int skq  = (tid & 3) * 8;  // 0,8,16,24
        const int wk   = tid >> 3;       // 0..31
        const int wu   = (tid & 7) * 8;  // 0..56

        if (tid < 64) { reds[tid] = 0.f; redn[tid] = 0.f; }

        float acc[4][4];
        #pragma unroll
        for (int a = 0; a < 4; ++a)
            #pragma unroll
            for (int b = 0; b < 4; ++b) acc[a][b] = 0.f;

        for (int k0 = 0; k0 < FIN; k0 += 32) {
            __syncthreads();
            {
                const float4* xp = reinterpret_cast<const float4*>(
                    X + (size_t)(r0 + srow) * FIN + k0 + skq);
                const float4 x0 = xp[0], x1 = xp[1];
                const float xs[8] = {x0.x, x0.y, x0.z, x0.w, x1.x, x1.y, x1.z, x1.w};
                #pragma unroll
                for (int m = 0; m < 8; ++m) Xt[(skq + m) * 68 + srow] = xs[m];
            }
            {
                const float4* wp = reinterpret_cast<const float4*>(
                    W + (size_t)h * (FIN * UNITS) + (size_t)(k0 + wk) * UNITS + wu);
                const float4 w0 = wp[0], w1 = wp[1];
                const float ws8[8] = {w0.x, w0.y, w0.z, w0.w, w1.x, w1.y, w1.z, w1.w};
                #pragma unroll
                for (int m = 0; m < 8; ++m) Wl[wk * 68 + wu + m] = ws8[m];
            }
            __syncthreads();
            #pragma unroll 8
            for (int k = 0; k < 32; ++k) {
                const float4 a4 = *reinterpret_cast<const float4*>(&Xt[k * 68 + r]);
                const float4 b4 = *reinterpret_cast<const float4*>(&Wl[k * 68 + cl]);
                const float av[4] = {a4.x, a4.y, a4.z, a4.w};
                const float bv[4] = {b4.x, b4.y, b4.z, b4.w};
                #pragma unroll
                for (int ri = 0; ri < 4; ++ri)
                    #pragma unroll
                    for (int ci = 0; ci < 4; ++ci)
                        acc[ri][ci] += av[ri] * bv[ci];
            }
        }

        float as4[4], an4[4];
        #pragma unroll
        for (int ci = 0; ci < 4; ++ci) {
            as4[ci] = atts[h * UNITS + cl + ci];
            an4[ci] = attn[h * UNITS + cl + ci];
        }
        #pragma unroll
        for (int ri = 0; ri < 4; ++ri) {
            float4 o = make_float4(acc[ri][0], acc[ri][1], acc[ri][2], acc[ri][3]);
            *reinterpret_cast<float4*>(&feats[(size_t)(r0 + r + ri) * CTOT + h * UNITS + cl]) = o;
            const float ps = acc[ri][0] * as4[0] + acc[ri][1] * as4[1]
                           + acc[ri][2] * as4[2] + acc[ri][3] * as4[3];
            const float pn = acc[ri][0] * an4[0] + acc[ri][1] * an4[1]
                           + acc[ri][2] * an4[2] + acc[ri][3] * an4[3];
            atomicAdd(&reds[r + ri], ps);   // LDS ds_add, 16-way per row
            atomicAdd(&redn[r + ri], pn);
        }
        __syncthreads();
        if (tid < 64) {
            s_self [((size_t)(r0 + tid) << 2) + h] = reds[tid];  // [n][4]
            s_neigh[((size_t)(r0 + tid) << 2) + h] = redn[tid];
        }
    }

    // ================= Phase A2: A-row scan / edge compaction =================
    // Static balance: GEMM blocks take 6 rows, scan-only blocks 10 rows.
    const int row0  = (bid < GBLK) ? bid * RA1 : GBLK * RA1 + (bid - GBLK) * RA2;
    const int nrows = (bid < GBLK) ? RA1 : RA2;
    for (int rr = 0; rr < nrows; ++rr) {
        const int i = row0 + rr;
        if (tid == 0) cnt = 0;
        __syncthreads();
        {
            const float4* Arow4 = reinterpret_cast<const float4*>(A + (size_t)i * NN);
            unsigned mask = 0;
            #pragma unroll
            for (int q = 0; q < 8; ++q) {        // 1 KB/wave/instr, coalesced
                const float4 v = Arow4[q * 256 + tid];
                mask |= (v.x != 0.f ? 1u : 0u) << (4 * q);
                mask |= (v.y != 0.f ? 1u : 0u) << (4 * q + 1);
                mask |= (v.z != 0.f ? 1u : 0u) << (4 * q + 2);
                mask |= (v.w != 0.f ? 1u : 0u) << (4 * q + 3);
            }
            const int c = __popc(mask);
            int base = 0;
            if (c) base = atomicAdd(&cnt, c);
            while (mask) {
                const int b = __ffs(mask) - 1;
                mask &= mask - 1;
                if (base < CAP) ej[base] = (b >> 2) * 1024 + tid * 4 + (b & 3);
                ++base;
            }
        }
        __syncthreads();
        const int ne = min(cnt, CAP);
        if (tid < ne) ej_g[(size_t)i * CAP + tid] = ej[tid];
        if (tid == 0) cnt_g[i] = ne;
        __syncthreads();                 // guard cnt/ej against next row's reset
    }

    // ============== grid-wide barrier (device-scope visibility) ==============
    __threadfence();                     // release feats/s_self/s_neigh/ej_g
    cg::this_grid().sync();
    __threadfence();                     // acquire (belt-and-braces, once)

    // ================= Phase B: per-row softmax + weighted gather =================
    const int w    = tid >> 6;           // wave == head
    const int lane = tid & 63;
    const int h4   = lane >> 4;          // head owning output cols 4*lane..+3
    for (int rq = 0; rq < RB; ++rq) {
        const int i  = bid * RB + rq;
        const int ne = cnt_g[i];
        if (tid < ne) ej[tid] = ej_g[(size_t)i * CAP + tid];
        __syncthreads();

        // ---- per-head softmax over edges (wave w == head w) ----
        const float si = s_self[((size_t)i << 2) + w];
        float m = -3.0e38f;
        for (int jj = lane; jj < ne; jj += 64) {
            const int j = ej[jj];
            float e = si + s_neigh[((size_t)j << 2) + w];
            e = (e > 0.f) ? e : 0.2f * e;            // leaky-relu(0.2)
            sc[w][jj] = e;
            m = fmaxf(m, e);
        }
        #pragma unroll
        for (int off = 32; off > 0; off >>= 1) m = fmaxf(m, __shfl_xor(m, off, 64));
        float l = 0.f;
        for (int jj = lane; jj < ne; jj += 64) {
            const float p = __expf(sc[w][jj] - m);
            sc[w][jj] = p;
            l += p;
        }
        #pragma unroll
        for (int off = 32; off > 0; off >>= 1) l += __shfl_xor(l, off, 64);
        if (lane == 0) rls[w] = 1.f / l;             // ne>=1 (self-loop)
        __syncthreads();

        // ---- weighted feats gather: wave = edge-slice, lane = 4 columns ----
        float4 o = make_float4(0.f, 0.f, 0.f, 0.f);
        int jj = w;
        for (; jj + 4 < ne; jj += 8) {               // 2 edges (jj, jj+4) per iter
            const int ja = ej[jj], jb = ej[jj + 4];
            const float pa = sc[h4][jj], pb = sc[h4][jj + 4];
            const float4 fa = *reinterpret_cast<const float4*>(
                &feats[(size_t)ja * CTOT + 4 * lane]);
            const float4 fc = *reinterpret_cast<const float4*>(
                &feats[(size_t)jb * CTOT + 4 * lane]);
            o.x += pa * fa.x + pb * fc.x;
            o.y += pa * fa.y + pb * fc.y;
            o.z += pa * fa.z + pb * fc.z;
            o.w += pa * fa.w + pb * fc.w;
        }
        if (jj < ne) {                               // <=1 remainder edge per wave
            const int ja = ej[jj];
            const float pa = sc[h4][jj];
            const float4 fa = *reinterpret_cast<const float4*>(
                &feats[(size_t)ja * CTOT + 4 * lane]);
            o.x += pa * fa.x; o.y += pa * fa.y; o.z += pa * fa.z; o.w += pa * fa.w;
        }
        *reinterpret_cast<float4*>(&part[w][4 * lane]) = o;
        __syncthreads();

        // ---- cross-wave reduce (4 partials), scale by 1/l, ELU, store ----
        float s = part[0][tid] + part[1][tid] + part[2][tid] + part[3][tid];
        s *= rls[tid >> 6];
        out[(size_t)i * CTOT + tid] = (s > 0.f) ? s : (__expf(s) - 1.f);  // ELU
        __syncthreads();                 // guard ej/sc/part before next row
    }
}

// ---------------------------------------------------------------------------
// Fallback 2-kernel path (round-0 structure) in case cooperative launch fails.
// ---------------------------------------------------------------------------
#define PBLK  512
__global__ __launch_bounds__(256) void k_proj_scan(const float* __restrict__ X,
                                                   const float* __restrict__ W,
                                                   const float* __restrict__ atts,
                                                   const float* __restrict__ attn,
                                                   const float* __restrict__ A,
                                                   float* __restrict__ feats,
                                                   float* __restrict__ s_self,
                                                   float* __restrict__ s_neigh,
                                                   int*   __restrict__ ej_g,
                                                   int*   __restrict__ cnt_g) {
    const int tid = threadIdx.x;
    const int bid = blockIdx.x;

    if (bid >= PBLK) {
        __shared__ int ej[CAP];
        __shared__ int cnt;
        const int i = bid - PBLK;
        if (tid == 0) cnt = 0;
        __syncthreads();
        {
            const float4* Arow4 = reinterpret_cast<const float4*>(A + (size_t)i * NN);
            unsigned mask = 0;
            #pragma unroll
            for (int q = 0; q < 8; ++q) {
                const float4 v = Arow4[q * 256 + tid];
                mask |= (v.x != 0.f ? 1u : 0u) << (4 * q);
                mask |= (v.y != 0.f ? 1u : 0u) << (4 * q + 1);
                mask |= (v.z != 0.f ? 1u : 0u) << (4 * q + 2);
                mask |= (v.w != 0.f ? 1u : 0u) << (4 * q + 3);
            }
            const int c = __popc(mask);
            int base = 0;
            if (c) base = atomicAdd(&cnt, c);
            while (mask) {
                const int b = __ffs(mask) - 1;
                mask &= mask - 1;
                if (base < CAP) ej[base] = (b >> 2) * 1024 + tid * 4 + (b & 3);
                ++base;
            }
        }
        __syncthreads();
        const int ne = min(cnt, CAP);
        if (tid < ne) ej_g[(size_t)i * CAP + tid] = ej[tid];
        if (tid == 0) cnt_g[i] = ne;
        return;
    }

    __shared__ float Xt[32 * 68];
    __shared__ float Wl[32 * 68];
    __shared__ float reds[64];
    __shared__ float redn[64];
    const int rt = bid & 127;
    const int h  = bid >> 7;
    const int r0 = rt * 64;
    const int r  = (tid & 15) * 4;
    const int cl = (tid >> 4) * 4;
    const int srow = tid >> 2;
    const int skq  = (tid & 3) * 8;
    const int wk   = tid >> 3;
    const int wu   = (tid & 7) * 8;

    if (tid < 64) { reds[tid] = 0.f; redn[tid] = 0.f; }

    float acc[4][4];
    #pragma unroll
    for (int a = 0; a < 4; ++a)
        #pragma unroll
        for (int b = 0; b < 4; ++b) acc[a][b] = 0.f;

    for (int k0 = 0; k0 < FIN; k0 += 32) {
        __syncthreads();
        {
            const float4* xp = reinterpret_cast<const float4*>(
                X + (size_t)(r0 + srow) * FIN + k0 + skq);
            const float4 x0 = xp[0], x1 = xp[1];
            const float xs[8] = {x0.x, x0.y, x0.z, x0.w, x1.x, x1.y, x1.z, x1.w};
            #pragma unroll
            for (int m = 0; m < 8; ++m) Xt[(skq + m) * 68 + srow] = xs[m];
        }
        {
            const float4* wp = reinterpret_cast<const float4*>(
                W + (size_t)h * (FIN * UNITS) + (size_t)(k0 + wk) * UNITS + wu);
            const float4 w0 = wp[0], w1 = wp[1];
            const float ws8[8] = {w0.x, w0.y, w0.z, w0.w, w1.x, w1.y, w1.z, w1.w};
            #pragma unroll
            for (int m = 0; m < 8; ++m) Wl[wk * 68 + wu + m] = ws8[m];
        }
        __syncthreads();
        #pragma unroll 8
        for (int k = 0; k < 32; ++k) {
            const float4 a4 = *reinterpret_cast<const float4*>(&Xt[k * 68 + r]);
            const float4 b4 = *reinterpret_cast<const float4*>(&Wl[k * 68 + cl]);
            const float av[4] = {a4.x, a4.y, a4.z, a4.w};
            const float bv[4] = {b4.x, b4.y, b4.z, b4.w};
            #pragma unroll
            for (int ri = 0; ri < 4; ++ri)
                #pragma unroll
                for (int ci = 0; ci < 4; ++ci)
                    acc[ri][ci] += av[ri] * bv[ci];
        }
    }

    float as4[4], an4[4];
    #pragma unroll
    for (int ci = 0; ci < 4; ++ci) {
        as4[ci] = atts[h * UNITS + cl + ci];
        an4[ci] = attn[h * UNITS + cl + ci];
    }
    #pragma unroll
    for (int ri = 0; ri < 4; ++ri) {
        float4 o = make_float4(acc[ri][0], acc[ri][1], acc[ri][2], acc[ri][3]);
        *reinterpret_cast<float4*>(&feats[(size_t)(r0 + r + ri) * CTOT + h * UNITS + cl]) = o;
        const float ps = acc[ri][0] * as4[0] + acc[ri][1] * as4[1]
                       + acc[ri][2] * as4[2] + acc[ri][3] * as4[3];
        const float pn = acc[ri][0] * an4[0] + acc[ri][1] * an4[1]
                       + acc[ri][2] * an4[2] + acc[ri][3] * an4[3];
        atomicAdd(&reds[r + ri], ps);
        atomicAdd(&redn[r + ri], pn);
    }
    __syncthreads();
    if (tid < 64) {
        s_self [((size_t)(r0 + tid) << 2) + h] = reds[tid];
        s_neigh[((size_t)(r0 + tid) << 2) + h] = redn[tid];
    }
}

__global__ __launch_bounds__(256) void k_gat(const int*   __restrict__ ej_g,
                                             const int*   __restrict__ cnt_g,
                                             const float* __restrict__ feats,
                                             const float* __restrict__ s_self,
                                             const float* __restrict__ s_neigh,
                                             float* __restrict__ out) {
    __shared__ int   ej[CAP];
    __shared__ float sc[HEADS][CAP];
    __shared__ float part[HEADS][CTOT];
    __shared__ float rls[HEADS];
    const int tid = threadIdx.x;
    const int i   = blockIdx.x;
    const int ne  = cnt_g[i];
    if (tid < ne) ej[tid] = ej_g[(size_t)i * CAP + tid];
    __syncthreads();

    const int w    = tid >> 6;
    const int lane = tid & 63;
    const float si = s_self[((size_t)i << 2) + w];
    float m = -3.0e38f;
    for (int jj = lane; jj < ne; jj += 64) {
        const int j = ej[jj];
        float e = si + s_neigh[((size_t)j << 2) + w];
        e = (e > 0.f) ? e : 0.2f * e;
        sc[w][jj] = e;
        m = fmaxf(m, e);
    }
    #pragma unroll
    for (int off = 32; off > 0; off >>= 1) m = fmaxf(m, __shfl_xor(m, off, 64));
    float l = 0.f;
    for (int jj = lane; jj < ne; jj += 64) {
        const float p = __expf(sc[w][jj] - m);
        sc[w][jj] = p;
        l += p;
    }
    #pragma unroll
    for (int off = 32; off > 0; off >>= 1) l += __shfl_xor(l, off, 64);
    if (lane == 0) rls[w] = 1.f / l;
    __syncthreads();

    const int h4 = lane >> 4;
    float4 o = make_float4(0.f, 0.f, 0.f, 0.f);
    int jj = w;
    for (; jj + 4 < ne; jj += 8) {
        const int ja = ej[jj], jb = ej[jj + 4];
        const float pa = sc[h4][jj], pb = sc[h4][jj + 4];
        const float4 fa = *reinterpret_cast<const float4*>(
            &feats[(size_t)ja * CTOT + 4 * lane]);
        const float4 fc = *reinterpret_cast<const float4*>(
            &feats[(size_t)jb * CTOT + 4 * lane]);
        o.x += pa * fa.x + pb * fc.x;
        o.y += pa * fa.y + pb * fc.y;
        o.z += pa * fa.z + pb * fc.z;
        o.w += pa * fa.w + pb * fc.w;
    }
    if (jj < ne) {
        const int ja = ej[jj];
        const float pa = sc[h4][jj];
        const float4 fa = *reinterpret_cast<const float4*>(
            &feats[(size_t)ja * CTOT + 4 * lane]);
        o.x += pa * fa.x; o.y += pa * fa.y; o.z += pa * fa.z; o.w += pa * fa.w;
    }
    *reinterpret_cast<float4*>(&part[w][4 * lane]) = o;
    __syncthreads();

    float s = part[0][tid] + part[1][tid] + part[2][tid] + part[3][tid];
    s *= rls[tid >> 6];
    out[(size_t)i * CTOT + tid] = (s > 0.f) ? s : (__expf(s) - 1.f);
}

// ---------------------------------------------------------------------------
extern "C" void kernel_launch(void* const* d_in, const int* in_sizes, int n_in,
                              void* d_out, int out_size, void* d_ws, size_t ws_size,
                              hipStream_t stream) {
    const float* X    = (const float*)d_in[0];
    const float* A    = (const float*)d_in[1];
    const float* W    = (const float*)d_in[2];
    const float* atts = (const float*)d_in[3];
    const float* attn = (const float*)d_in[4];

    float* feats   = (float*)d_ws;                      // NN*CTOT fp32 = 8 MB
    float* s_self  = feats  + (size_t)NN * CTOT;        // NN*4 fp32
    float* s_neigh = s_self + (size_t)NN * HEADS;       // NN*4 fp32
    int*   cnt_g   = (int*)(s_neigh + (size_t)NN * HEADS);   // NN ints
    int*   ej_g    = cnt_g + NN;                        // NN*CAP ints = 8 MB
    float* out     = (float*)d_out;

    void* args[] = {(void*)&X, (void*)&W, (void*)&atts, (void*)&attn, (void*)&A,
                    (void*)&feats, (void*)&s_self, (void*)&s_neigh,
                    (void*)&ej_g, (void*)&cnt_g, (void*)&out};
    hipError_t e = hipLaunchCooperativeKernel((const void*)k_fused,
                                              dim3(GRID), dim3(256),
                                              args, 0, stream);
    if (e != hipSuccess) {
        // Fallback: proven round-0 two-kernel path
        k_proj_scan<<<PBLK + NN, 256, 0, stream>>>(X, W, atts, attn, A,
                                                   feats, s_self, s_neigh, ej_g, cnt_g);
        k_gat<<<NN, 256, 0, stream>>>(ej_g, cnt_g, feats, s_self, s_neigh, out);
    }
}

// Round 3
// 396.735 us; speedup vs baseline: 1.8462x; 1.8462x over previous
//
#include <hip/hip_runtime.h>

// Problem constants (all inputs/outputs fp32)
#define NN    8192   // nodes
#define FIN   256    // input features
#define UNITS 64
#define HEADS 4
#define CTOT  256    // HEADS*UNITS
#define CAP   256    // max edges/row (deg ~ Bin(8192,.004)+self: mean 34, sd 5.7)
#define GBLK  512    // GEMM blocks (128 row-tiles x 4 heads)

// ---------------------------------------------------------------------------
// Kernel 1 — projection GEMM only (round-1's proven GEMM branch, 512 blocks).
// VALU-bound, ~2.1 GFLOP; runs exposed (~20 µs) now that the A-scan moved to
// kernel 2 where it overlaps the LLC-bound gather instead.
// ---------------------------------------------------------------------------
__global__ __launch_bounds__(256) void k_proj(const float* __restrict__ X,
                                              const float* __restrict__ W,
                                              const float* __restrict__ atts,
                                              const float* __restrict__ attn,
                                              float* __restrict__ feats,
                                              float* __restrict__ s_self,
                                              float* __restrict__ s_neigh) {
    __shared__ float Xt[32 * 68];   // [k][row], stride 68
    __shared__ float Wl[32 * 68];   // [k][u]
    __shared__ float reds[64];
    __shared__ float redn[64];
    const int tid = threadIdx.x;
    const int bid = blockIdx.x;
    const int rt = bid & 127;        // row tile
    const int h  = bid >> 7;         // head
    const int r0 = rt * 64;

    const int r  = (tid & 15) * 4;   // micro-tile row base
    const int cl = (tid >> 4) * 4;   // micro-tile col base
    const int srow = tid >> 2;       // 0..63
    const int skq  = (tid & 3) * 8;  // 0,8,16,24
    const int wk   = tid >> 3;       // 0..31
    const int wu   = (tid & 7) * 8;  // 0..56

    if (tid < 64) { reds[tid] = 0.f; redn[tid] = 0.f; }

    float acc[4][4];
    #pragma unroll
    for (int a = 0; a < 4; ++a)
        #pragma unroll
        for (int b = 0; b < 4; ++b) acc[a][b] = 0.f;

    for (int k0 = 0; k0 < FIN; k0 += 32) {
        __syncthreads();
        {
            const float4* xp = reinterpret_cast<const float4*>(
                X + (size_t)(r0 + srow) * FIN + k0 + skq);
            const float4 x0 = xp[0], x1 = xp[1];
            const float xs[8] = {x0.x, x0.y, x0.z, x0.w, x1.x, x1.y, x1.z, x1.w};
            #pragma unroll
            for (int m = 0; m < 8; ++m) Xt[(skq + m) * 68 + srow] = xs[m];
        }
        {
            const float4* wp = reinterpret_cast<const float4*>(
                W + (size_t)h * (FIN * UNITS) + (size_t)(k0 + wk) * UNITS + wu);
            const float4 w0 = wp[0], w1 = wp[1];
            const float ws8[8] = {w0.x, w0.y, w0.z, w0.w, w1.x, w1.y, w1.z, w1.w};
            #pragma unroll
            for (int m = 0; m < 8; ++m) Wl[wk * 68 + wu + m] = ws8[m];
        }
        __syncthreads();
        #pragma unroll 8
        for (int k = 0; k < 32; ++k) {
            const float4 a4 = *reinterpret_cast<const float4*>(&Xt[k * 68 + r]);
            const float4 b4 = *reinterpret_cast<const float4*>(&Wl[k * 68 + cl]);
            const float av[4] = {a4.x, a4.y, a4.z, a4.w};
            const float bv[4] = {b4.x, b4.y, b4.z, b4.w};
            #pragma unroll
            for (int ri = 0; ri < 4; ++ri)
                #pragma unroll
                for (int ci = 0; ci < 4; ++ci)
                    acc[ri][ci] += av[ri] * bv[ci];
        }
    }

    float as4[4], an4[4];
    #pragma unroll
    for (int ci = 0; ci < 4; ++ci) {
        as4[ci] = atts[h * UNITS + cl + ci];
        an4[ci] = attn[h * UNITS + cl + ci];
    }
    #pragma unroll
    for (int ri = 0; ri < 4; ++ri) {
        float4 o = make_float4(acc[ri][0], acc[ri][1], acc[ri][2], acc[ri][3]);
        *reinterpret_cast<float4*>(&feats[(size_t)(r0 + r + ri) * CTOT + h * UNITS + cl]) = o;
        const float ps = acc[ri][0] * as4[0] + acc[ri][1] * as4[1]
                       + acc[ri][2] * as4[2] + acc[ri][3] * as4[3];
        const float pn = acc[ri][0] * an4[0] + acc[ri][1] * an4[1]
                       + acc[ri][2] * an4[2] + acc[ri][3] * an4[3];
        atomicAdd(&reds[r + ri], ps);   // LDS ds_add, 16-way per row
        atomicAdd(&redn[r + ri], pn);
    }
    __syncthreads();
    if (tid < 64) {
        s_self [((size_t)(r0 + tid) << 2) + h] = reds[tid];  // [n][4]
        s_neigh[((size_t)(r0 + tid) << 2) + h] = redn[tid];
    }
}

// ---------------------------------------------------------------------------
// Kernel 2 — fused scan + softmax + gather (8192 blocks, one A-row each).
// The 256 MB HBM-bound A-scan now overlaps the LLC-bound feats gather across
// blocks at different phases (round-5's heterogeneous-overlap trick, applied
// to the scan/gather pair). Edge list lives only in LDS — no ej_g round-trip.
// ---------------------------------------------------------------------------
__global__ __launch_bounds__(256) void k_scan_gat(const float* __restrict__ A,
                                                  const float* __restrict__ feats,
                                                  const float* __restrict__ s_self,
                                                  const float* __restrict__ s_neigh,
                                                  float* __restrict__ out) {
    __shared__ int   ej[CAP];
    __shared__ int   cnt;
    __shared__ float sc[HEADS][CAP];
    __shared__ float part[HEADS][CTOT];
    __shared__ float rls[HEADS];
    const int tid = threadIdx.x;
    const int i   = blockIdx.x;

    // ---- A-row scan / edge compaction (HBM-bound, 32 KB coalesced) ----
    if (tid == 0) cnt = 0;
    __syncthreads();
    {
        const float4* Arow4 = reinterpret_cast<const float4*>(A + (size_t)i * NN);
        unsigned mask = 0;
        #pragma unroll
        for (int q = 0; q < 8; ++q) {        // 1 KB/wave/instr, coalesced
            const float4 v = Arow4[q * 256 + tid];
            mask |= (v.x != 0.f ? 1u : 0u) << (4 * q);
            mask |= (v.y != 0.f ? 1u : 0u) << (4 * q + 1);
            mask |= (v.z != 0.f ? 1u : 0u) << (4 * q + 2);
            mask |= (v.w != 0.f ? 1u : 0u) << (4 * q + 3);
        }
        const int c = __popc(mask);
        int base = 0;
        if (c) base = atomicAdd(&cnt, c);
        while (mask) {
            const int b = __ffs(mask) - 1;
            mask &= mask - 1;
            if (base < CAP) ej[base] = (b >> 2) * 1024 + tid * 4 + (b & 3);
            ++base;
        }
    }
    __syncthreads();
    const int ne = min(cnt, CAP);

    // ---- per-head softmax over edges (wave w == head w) ----
    const int w    = tid >> 6;
    const int lane = tid & 63;
    const float si = s_self[((size_t)i << 2) + w];
    float m = -3.0e38f;
    for (int jj = lane; jj < ne; jj += 64) {
        const int j = ej[jj];
        float e = si + s_neigh[((size_t)j << 2) + w];
        e = (e > 0.f) ? e : 0.2f * e;            // leaky-relu(0.2)
        sc[w][jj] = e;
        m = fmaxf(m, e);
    }
    #pragma unroll
    for (int off = 32; off > 0; off >>= 1) m = fmaxf(m, __shfl_xor(m, off, 64));
    float l = 0.f;
    for (int jj = lane; jj < ne; jj += 64) {
        const float p = __expf(sc[w][jj] - m);
        sc[w][jj] = p;
        l += p;
    }
    #pragma unroll
    for (int off = 32; off > 0; off >>= 1) l += __shfl_xor(l, off, 64);
    if (lane == 0) rls[w] = 1.f / l;             // ne>=1 (self-loop)
    __syncthreads();

    // ---- weighted feats gather: wave = edge-slice, lane = 4 columns ----
    const int h4 = lane >> 4;                    // head owning cols 4*lane..+3
    float4 o = make_float4(0.f, 0.f, 0.f, 0.f);
    int jj = w;
    for (; jj + 4 < ne; jj += 8) {               // 2 edges (jj, jj+4) per iter
        const int ja = ej[jj], jb = ej[jj + 4];
        const float pa = sc[h4][jj], pb = sc[h4][jj + 4];
        const float4 fa = *reinterpret_cast<const float4*>(
            &feats[(size_t)ja * CTOT + 4 * lane]);
        const float4 fc = *reinterpret_cast<const float4*>(
            &feats[(size_t)jb * CTOT + 4 * lane]);
        o.x += pa * fa.x + pb * fc.x;
        o.y += pa * fa.y + pb * fc.y;
        o.z += pa * fa.z + pb * fc.z;
        o.w += pa * fa.w + pb * fc.w;
    }
    if (jj < ne) {                               // <=1 remainder edge per wave
        const int ja = ej[jj];
        const float pa = sc[h4][jj];
        const float4 fa = *reinterpret_cast<const float4*>(
            &feats[(size_t)ja * CTOT + 4 * lane]);
        o.x += pa * fa.x; o.y += pa * fa.y; o.z += pa * fa.z; o.w += pa * fa.w;
    }
    *reinterpret_cast<float4*>(&part[w][4 * lane]) = o;
    __syncthreads();

    // ---- cross-wave reduce (4 partials), scale by 1/l, ELU, store ----
    float s = part[0][tid] + part[1][tid] + part[2][tid] + part[3][tid];
    s *= rls[tid >> 6];
    out[(size_t)i * CTOT + tid] = (s > 0.f) ? s : (__expf(s) - 1.f);   // ELU
}

// ---------------------------------------------------------------------------
extern "C" void kernel_launch(void* const* d_in, const int* in_sizes, int n_in,
                              void* d_out, int out_size, void* d_ws, size_t ws_size,
                              hipStream_t stream) {
    const float* X    = (const float*)d_in[0];
    const float* A    = (const float*)d_in[1];
    const float* W    = (const float*)d_in[2];
    const float* atts = (const float*)d_in[3];
    const float* attn = (const float*)d_in[4];

    float* feats   = (float*)d_ws;                      // NN*CTOT fp32 = 8 MB
    float* s_self  = feats  + (size_t)NN * CTOT;        // NN*4 fp32
    float* s_neigh = s_self + (size_t)NN * HEADS;       // NN*4 fp32

    k_proj<<<GBLK, 256, 0, stream>>>(X, W, atts, attn, feats, s_self, s_neigh);
    k_scan_gat<<<NN, 256, 0, stream>>>(A, feats, s_self, s_neigh, (float*)d_out);
}

// Round 4
// 394.331 us; speedup vs baseline: 1.8575x; 1.0061x over previous
//
#include <hip/hip_runtime.h>

// Problem constants (all inputs/outputs fp32)
#define NN    8192   // nodes
#define FIN   256    // input features
#define UNITS 64
#define HEADS 4
#define CTOT  256    // HEADS*UNITS
#define CAP   256    // max edges/row (deg ~ Bin(8192,.004)+self: mean 34, sd 5.7)
#define GBLK  512    // GEMM blocks (128 row-tiles x 4 heads)
#define HALF  4096   // pipeline chunk = NN/2

// ---------------------------------------------------------------------------
// Proven components (byte-identical code paths), re-arranged as a 3-stage
// software pipeline so the row-i gather overlaps the row-(i+HALF) scan:
//   k_pipe1: GEMM (512 blk)  ∥  scan rows [0,HALF)      -> ej_g/cnt_g
//   k_pipe2: scan rows [HALF,NN)  ∥  gather rows [0,HALF)
//   k_pipe3: gather rows [HALF,NN)
// gather(i) depends on {feats, s_self, s_neigh} (k1 GEMM) + scan(i) only,
// so each stage's inputs are complete when it launches.
// ---------------------------------------------------------------------------

__device__ __forceinline__ void scan_row(const float* __restrict__ A, int i,
                                         int* __restrict__ ej_g,
                                         int* __restrict__ cnt_g,
                                         int* ej, int* cnt) {
    const int tid = threadIdx.x;
    if (tid == 0) *cnt = 0;
    __syncthreads();
    {
        const float4* Arow4 = reinterpret_cast<const float4*>(A + (size_t)i * NN);
        unsigned mask = 0;
        #pragma unroll
        for (int q = 0; q < 8; ++q) {        // 1 KB/wave/instr, coalesced
            const float4 v = Arow4[q * 256 + tid];
            mask |= (v.x != 0.f ? 1u : 0u) << (4 * q);
            mask |= (v.y != 0.f ? 1u : 0u) << (4 * q + 1);
            mask |= (v.z != 0.f ? 1u : 0u) << (4 * q + 2);
            mask |= (v.w != 0.f ? 1u : 0u) << (4 * q + 3);
        }
        const int c = __popc(mask);
        int base = 0;
        if (c) base = atomicAdd(cnt, c);
        while (mask) {
            const int b = __ffs(mask) - 1;
            mask &= mask - 1;
            if (base < CAP) ej[base] = (b >> 2) * 1024 + tid * 4 + (b & 3);
            ++base;
        }
    }
    __syncthreads();
    const int ne = min(*cnt, CAP);
    if (tid < ne) ej_g[(size_t)i * CAP + tid] = ej[tid];
    if (tid == 0) cnt_g[i] = ne;
}

__device__ __forceinline__ void gat_row(int i,
                                        const int* __restrict__ ej_g,
                                        const int* __restrict__ cnt_g,
                                        const float* __restrict__ feats,
                                        const float* __restrict__ s_self,
                                        const float* __restrict__ s_neigh,
                                        float* __restrict__ out,
                                        int* ej, float (*sc)[CAP],
                                        float (*part)[CTOT], float* rls) {
    const int tid = threadIdx.x;
    const int ne  = cnt_g[i];
    if (tid < ne) ej[tid] = ej_g[(size_t)i * CAP + tid];
    __syncthreads();

    // ---- per-head softmax over edges (wave w == head w) ----
    const int w    = tid >> 6;
    const int lane = tid & 63;
    const float si = s_self[((size_t)i << 2) + w];
    float m = -3.0e38f;
    for (int jj = lane; jj < ne; jj += 64) {
        const int j = ej[jj];
        float e = si + s_neigh[((size_t)j << 2) + w];
        e = (e > 0.f) ? e : 0.2f * e;            // leaky-relu(0.2)
        sc[w][jj] = e;
        m = fmaxf(m, e);
    }
    #pragma unroll
    for (int off = 32; off > 0; off >>= 1) m = fmaxf(m, __shfl_xor(m, off, 64));
    float l = 0.f;
    for (int jj = lane; jj < ne; jj += 64) {
        const float p = __expf(sc[w][jj] - m);
        sc[w][jj] = p;
        l += p;
    }
    #pragma unroll
    for (int off = 32; off > 0; off >>= 1) l += __shfl_xor(l, off, 64);
    if (lane == 0) rls[w] = 1.f / l;             // ne>=1 (self-loop)
    __syncthreads();

    // ---- weighted feats gather: wave = edge-slice, lane = 4 columns ----
    const int h4 = lane >> 4;                    // head owning cols 4*lane..+3
    float4 o = make_float4(0.f, 0.f, 0.f, 0.f);
    int jj = w;
    for (; jj + 4 < ne; jj += 8) {               // 2 edges (jj, jj+4) per iter
        const int ja = ej[jj], jb = ej[jj + 4];
        const float pa = sc[h4][jj], pb = sc[h4][jj + 4];
        const float4 fa = *reinterpret_cast<const float4*>(
            &feats[(size_t)ja * CTOT + 4 * lane]);
        const float4 fc = *reinterpret_cast<const float4*>(
            &feats[(size_t)jb * CTOT + 4 * lane]);
        o.x += pa * fa.x + pb * fc.x;
        o.y += pa * fa.y + pb * fc.y;
        o.z += pa * fa.z + pb * fc.z;
        o.w += pa * fa.w + pb * fc.w;
    }
    if (jj < ne) {                               // <=1 remainder edge per wave
        const int ja = ej[jj];
        const float pa = sc[h4][jj];
        const float4 fa = *reinterpret_cast<const float4*>(
            &feats[(size_t)ja * CTOT + 4 * lane]);
        o.x += pa * fa.x; o.y += pa * fa.y; o.z += pa * fa.z; o.w += pa * fa.w;
    }
    *reinterpret_cast<float4*>(&part[w][4 * lane]) = o;
    __syncthreads();

    // ---- cross-wave reduce (4 partials), scale by 1/l, ELU, store ----
    float s = part[0][tid] + part[1][tid] + part[2][tid] + part[3][tid];
    s *= rls[tid >> 6];
    out[(size_t)i * CTOT + tid] = (s > 0.f) ? s : (__expf(s) - 1.f);   // ELU
}

// ---------------------------------------------------------------------------
// Stage 1: GEMM (blocks < GBLK)  ∥  scan rows [0, HALF)
// ---------------------------------------------------------------------------
__global__ __launch_bounds__(256) void k_pipe1(const float* __restrict__ X,
                                               const float* __restrict__ W,
                                               const float* __restrict__ atts,
                                               const float* __restrict__ attn,
                                               const float* __restrict__ A,
                                               float* __restrict__ feats,
                                               float* __restrict__ s_self,
                                               float* __restrict__ s_neigh,
                                               int*   __restrict__ ej_g,
                                               int*   __restrict__ cnt_g) {
    const int tid = threadIdx.x;
    const int bid = blockIdx.x;

    if (bid >= GBLK) {
        __shared__ int ej[CAP];
        __shared__ int cnt;
        scan_row(A, bid - GBLK, ej_g, cnt_g, ej, &cnt);
        return;
    }

    // ===================== projection GEMM (one head-tile) =====================
    __shared__ float Xt[32 * 68];   // [k][row], stride 68
    __shared__ float Wl[32 * 68];   // [k][u]
    __shared__ float reds[64];
    __shared__ float redn[64];
    const int rt = bid & 127;        // row tile
    const int h  = bid >> 7;         // head
    const int r0 = rt * 64;

    const int r  = (tid & 15) * 4;   // micro-tile row base
    const int cl = (tid >> 4) * 4;   // micro-tile col base
    const int srow = tid >> 2;       // 0..63
    const int skq  = (tid & 3) * 8;  // 0,8,16,24
    const int wk   = tid >> 3;       // 0..31
    const int wu   = (tid & 7) * 8;  // 0..56

    if (tid < 64) { reds[tid] = 0.f; redn[tid] = 0.f; }

    float acc[4][4];
    #pragma unroll
    for (int a = 0; a < 4; ++a)
        #pragma unroll
        for (int b = 0; b < 4; ++b) acc[a][b] = 0.f;

    for (int k0 = 0; k0 < FIN; k0 += 32) {
        __syncthreads();
        {
            const float4* xp = reinterpret_cast<const float4*>(
                X + (size_t)(r0 + srow) * FIN + k0 + skq);
            const float4 x0 = xp[0], x1 = xp[1];
            const float xs[8] = {x0.x, x0.y, x0.z, x0.w, x1.x, x1.y, x1.z, x1.w};
            #pragma unroll
            for (int m = 0; m < 8; ++m) Xt[(skq + m) * 68 + srow] = xs[m];
        }
        {
            const float4* wp = reinterpret_cast<const float4*>(
                W + (size_t)h * (FIN * UNITS) + (size_t)(k0 + wk) * UNITS + wu);
            const float4 w0 = wp[0], w1 = wp[1];
            const float ws8[8] = {w0.x, w0.y, w0.z, w0.w, w1.x, w1.y, w1.z, w1.w};
            #pragma unroll
            for (int m = 0; m < 8; ++m) Wl[wk * 68 + wu + m] = ws8[m];
        }
        __syncthreads();
        #pragma unroll 8
        for (int k = 0; k < 32; ++k) {
            const float4 a4 = *reinterpret_cast<const float4*>(&Xt[k * 68 + r]);
            const float4 b4 = *reinterpret_cast<const float4*>(&Wl[k * 68 + cl]);
            const float av[4] = {a4.x, a4.y, a4.z, a4.w};
            const float bv[4] = {b4.x, b4.y, b4.z, b4.w};
            #pragma unroll
            for (int ri = 0; ri < 4; ++ri)
                #pragma unroll
                for (int ci = 0; ci < 4; ++ci)
                    acc[ri][ci] += av[ri] * bv[ci];
        }
    }

    float as4[4], an4[4];
    #pragma unroll
    for (int ci = 0; ci < 4; ++ci) {
        as4[ci] = atts[h * UNITS + cl + ci];
        an4[ci] = attn[h * UNITS + cl + ci];
    }
    #pragma unroll
    for (int ri = 0; ri < 4; ++ri) {
        float4 o = make_float4(acc[ri][0], acc[ri][1], acc[ri][2], acc[ri][3]);
        *reinterpret_cast<float4*>(&feats[(size_t)(r0 + r + ri) * CTOT + h * UNITS + cl]) = o;
        const float ps = acc[ri][0] * as4[0] + acc[ri][1] * as4[1]
                       + acc[ri][2] * as4[2] + acc[ri][3] * as4[3];
        const float pn = acc[ri][0] * an4[0] + acc[ri][1] * an4[1]
                       + acc[ri][2] * an4[2] + acc[ri][3] * an4[3];
        atomicAdd(&reds[r + ri], ps);   // LDS ds_add, 16-way per row
        atomicAdd(&redn[r + ri], pn);
    }
    __syncthreads();
    if (tid < 64) {
        s_self [((size_t)(r0 + tid) << 2) + h] = reds[tid];  // [n][4]
        s_neigh[((size_t)(r0 + tid) << 2) + h] = redn[tid];
    }
}

// ---------------------------------------------------------------------------
// Stage 2: scan rows [HALF, NN) (blocks < HALF)  ∥  gather rows [0, HALF)
// Scan blocks come first in dispatch order so the HBM pipe fills immediately.
// ---------------------------------------------------------------------------
__global__ __launch_bounds__(256) void k_pipe2(const float* __restrict__ A,
                                               const int*   __restrict__ ej_g_ro,
                                               const int*   __restrict__ cnt_g_ro,
                                               int*   __restrict__ ej_g,
                                               int*   __restrict__ cnt_g,
                                               const float* __restrict__ feats,
                                               const float* __restrict__ s_self,
                                               const float* __restrict__ s_neigh,
                                               float* __restrict__ out) {
    const int bid = blockIdx.x;
    if (bid < HALF) {
        __shared__ int ej[CAP];
        __shared__ int cnt;
        scan_row(A, HALF + bid, ej_g, cnt_g, ej, &cnt);
    } else {
        __shared__ int   ej[CAP];
        __shared__ float sc[HEADS][CAP];
        __shared__ float part[HEADS][CTOT];
        __shared__ float rls[HEADS];
        gat_row(bid - HALF, ej_g_ro, cnt_g_ro, feats, s_self, s_neigh, out,
                ej, sc, part, rls);
    }
}

// ---------------------------------------------------------------------------
// Stage 3: gather rows [HALF, NN)
// ---------------------------------------------------------------------------
__global__ __launch_bounds__(256) void k_pipe3(const int*   __restrict__ ej_g,
                                               const int*   __restrict__ cnt_g,
                                               const float* __restrict__ feats,
                                               const float* __restrict__ s_self,
                                               const float* __restrict__ s_neigh,
                                               float* __restrict__ out) {
    __shared__ int   ej[CAP];
    __shared__ float sc[HEADS][CAP];
    __shared__ float part[HEADS][CTOT];
    __shared__ float rls[HEADS];
    gat_row(HALF + (int)blockIdx.x, ej_g, cnt_g, feats, s_self, s_neigh, out,
            ej, sc, part, rls);
}

// ---------------------------------------------------------------------------
extern "C" void kernel_launch(void* const* d_in, const int* in_sizes, int n_in,
                              void* d_out, int out_size, void* d_ws, size_t ws_size,
                              hipStream_t stream) {
    const float* X    = (const float*)d_in[0];
    const float* A    = (const float*)d_in[1];
    const float* W    = (const float*)d_in[2];
    const float* atts = (const float*)d_in[3];
    const float* attn = (const float*)d_in[4];

    float* feats   = (float*)d_ws;                      // NN*CTOT fp32 = 8 MB
    float* s_self  = feats  + (size_t)NN * CTOT;        // NN*4 fp32
    float* s_neigh = s_self + (size_t)NN * HEADS;       // NN*4 fp32
    int*   cnt_g   = (int*)(s_neigh + (size_t)NN * HEADS);   // NN ints
    int*   ej_g    = cnt_g + NN;                        // NN*CAP ints = 8 MB
    float* out     = (float*)d_out;

    k_pipe1<<<GBLK + HALF, 256, 0, stream>>>(X, W, atts, attn, A,
                                             feats, s_self, s_neigh, ej_g, cnt_g);
    k_pipe2<<<NN, 256, 0, stream>>>(A, ej_g, cnt_g, ej_g, cnt_g,
                                    feats, s_self, s_neigh, out);
    k_pipe3<<<HALF, 256, 0, stream>>>(ej_g, cnt_g, feats, s_self, s_neigh, out);
}